// Round 9
// baseline (302.935 us; speedup 1.0000x reference)
//
#include <hip/hip_runtime.h>
#include <math.h>

#define SS 2048
#define DD 1024
#define HH 16

typedef _Float16 f16;
typedef _Float16 half8 __attribute__((ext_vector_type(8)));
typedef _Float16 half4 __attribute__((ext_vector_type(4)));
typedef float f32x4 __attribute__((ext_vector_type(4)));
typedef unsigned long long u64;

#define LOG2E 1.44269504f
#define MASKNEG -30000.0f

__device__ __forceinline__ void gload16(const void* g, void* lds) {
    __builtin_amdgcn_global_load_lds(
        (const __attribute__((address_space(1))) unsigned int*)g,
        (__attribute__((address_space(3))) unsigned int*)lds, 16, 0, 0);
}

// ============================================================
// prep 1: f32 -> f16 elementwise for query/key/value
// ============================================================
__global__ __launch_bounds__(256)
void cvt_x(const float* __restrict__ q, const float* __restrict__ k,
           const float* __restrict__ v, f16* __restrict__ oq,
           f16* __restrict__ ok, f16* __restrict__ ov)
{
    const int z = blockIdx.z;
    const float* src = z == 0 ? q : z == 1 ? k : v;
    f16* dst = z == 0 ? oq : z == 1 ? ok : ov;
    size_t i = ((size_t)blockIdx.x * 256 + threadIdx.x) * 8;
    float4 v0 = *reinterpret_cast<const float4*>(src + i);
    float4 v1 = *reinterpret_cast<const float4*>(src + i + 4);
    half8 h;
    h[0] = (f16)v0.x; h[1] = (f16)v0.y; h[2] = (f16)v0.z; h[3] = (f16)v0.w;
    h[4] = (f16)v1.x; h[5] = (f16)v1.y; h[6] = (f16)v1.z; h[7] = (f16)v1.w;
    *reinterpret_cast<half8*>(dst + i) = h;
}

// ============================================================
// prep 2: W (k,n) f32 -> WT (n,k) f16, 64x64 tiles through LDS
// ============================================================
__global__ __launch_bounds__(256)
void cvt_wT(const float* __restrict__ wq, const float* __restrict__ wk,
            const float* __restrict__ wv, const float* __restrict__ wo,
            f16* __restrict__ oq, f16* __restrict__ ok,
            f16* __restrict__ ov, f16* __restrict__ oo)
{
    __shared__ float Lt[64][65];
    const int z = blockIdx.z;
    const float* W = z == 0 ? wq : z == 1 ? wk : z == 2 ? wv : wo;
    f16* WT = z == 0 ? oq : z == 1 ? ok : z == 2 ? ov : oo;
    const int n0 = blockIdx.x * 64, k0 = blockIdx.y * 64;
    const int t = threadIdx.x;
    {
        int row = t >> 2;               // k-local
        int c0  = (t & 3) * 16;         // n-local
#pragma unroll
        for (int u = 0; u < 4; ++u) {
            float4 x = *reinterpret_cast<const float4*>(
                &W[(size_t)(k0 + row) * DD + n0 + c0 + u * 4]);
            Lt[row][c0 + u * 4 + 0] = x.x;
            Lt[row][c0 + u * 4 + 1] = x.y;
            Lt[row][c0 + u * 4 + 2] = x.z;
            Lt[row][c0 + u * 4 + 3] = x.w;
        }
    }
    __syncthreads();
    {
        int n  = t >> 2;                // n-local
        int kc = (t & 3) * 16;          // k-local chunk
        half8 h0, h1;
#pragma unroll
        for (int u = 0; u < 8; ++u) h0[u] = (f16)Lt[kc + u][n];
#pragma unroll
        for (int u = 0; u < 8; ++u) h1[u] = (f16)Lt[kc + 8 + u][n];
        f16* dst = &WT[(size_t)(n0 + n) * DD + k0 + kc];
        *reinterpret_cast<half8*>(dst) = h0;
        *reinterpret_cast<half8*>(dst + 8) = h1;
    }
}

// ============================================================
// prep 3: rpb[j][i][h] f32 -> rpbT3[h][i][j'] f16 (scaled log2e),
// with j permuted WITHIN each 64-block: pos g*16+nt*4+reg holds the
// value for j = nt*16+4g+reg — so the attn kernel's lane (c,g) reads
// its 16 bias values as 2 contiguous half8 loads.
// ============================================================
__global__ __launch_bounds__(256)
void cvt_rpbT3(const float* __restrict__ rpb, f16* __restrict__ rpbT)
{
    __shared__ f16 Lt[16][16][66];   // [h][i][j-local], +2 pad
    const int t = threadIdx.x, wid = t >> 6, l = t & 63;
    const int i0 = blockIdx.x * 16;
    const int j0 = blockIdx.y * 64;
    const int il = l >> 2;
    const int h0 = (l & 3) * 4;
#pragma unroll
    for (int p = 0; p < 16; ++p) {
        int jl = p * 4 + wid;
        float4 v = *reinterpret_cast<const float4*>(
            rpb + ((size_t)(j0 + jl) * SS + i0 + il) * HH + h0);
        Lt[h0 + 0][il][jl] = (f16)(v.x * LOG2E);
        Lt[h0 + 1][il][jl] = (f16)(v.y * LOG2E);
        Lt[h0 + 2][il][jl] = (f16)(v.z * LOG2E);
        Lt[h0 + 3][il][jl] = (f16)(v.w * LOG2E);
    }
    __syncthreads();
    const int part = t & 7;
#pragma unroll
    for (int p = 0; p < 8; ++p) {
        int rowid = p * 32 + (t >> 3);
        int h = rowid >> 4, i2 = rowid & 15;
        half8 v;
#pragma unroll
        for (int e = 0; e < 8; ++e) {
            // out position q = part*8+e = g*16+nt*4+reg -> source j
            int sig = 32 * (part & 1) + 16 * (e >> 2) + 4 * (part >> 1) + (e & 3);
            v[e] = Lt[h][i2][sig];
        }
        *reinterpret_cast<half8*>(
            rpbT + ((size_t)h * SS + i0 + i2) * SS + j0 + part * 8) = v;
    }
}

// ============================================================
// prep 4: mask int32 -> bitmask u64[b*SS+i][j/64] via wave ballot.
// ============================================================
__global__ __launch_bounds__(256)
void cvt_maskbits(const int* __restrict__ mask, u64* __restrict__ mb)
{
    const int t = threadIdx.x, wid = t >> 6, l = t & 63;
    const int row = blockIdx.x * 4 + wid;     // b*SS+i
    const int* src = mask + (size_t)row * SS;
    u64* dst = mb + (size_t)row * 32;
    for (int it = 0; it < 32; ++it) {
        int mv = src[it * 64 + l];
        u64 bal = __ballot(mv != 0);
        if (l == 0) dst[it] = bal;
    }
}

// ============================================================
// Fused Q/K/V projection GEMM, f16 MFMA 16x16x32, 128x128 tile BK=64.
// ============================================================
__global__ __launch_bounds__(256)
void proj3(const f16* __restrict__ Xq, const f16* __restrict__ Xk,
           const f16* __restrict__ Xv, const f16* __restrict__ WqT,
           const f16* __restrict__ WkT, const f16* __restrict__ WvT,
           const float* __restrict__ bq, const float* __restrict__ bk,
           const float* __restrict__ bv,
           f16* __restrict__ Qo, f16* __restrict__ Ko, f16* __restrict__ VTo)
{
    __shared__ f16 As[128 * 64];
    __shared__ f16 Bs[128 * 64];
    const int t = threadIdx.x, wid = t >> 6, l = t & 63, c = l & 15, g = l >> 4;
    const int gz = blockIdx.z;
    const f16 *Ap, *Bp; const float* bias; int m0, n0;
    if (gz == 2) { Ap = WvT; Bp = Xv; bias = bv; m0 = blockIdx.x * 128; n0 = blockIdx.y * 128; }
    else if (gz == 1) { Ap = Xk; Bp = WkT; bias = bk; m0 = blockIdx.y * 128; n0 = blockIdx.x * 128; }
    else { Ap = Xq; Bp = WqT; bias = bq; m0 = blockIdx.y * 128; n0 = blockIdx.x * 128; }
    const int wm = wid >> 1, wn = wid & 1;
    f32x4 acc[4][4] = {};
    char* AsB = (char*)As; char* BsB = (char*)Bs;

    for (int k0 = 0; k0 < DD; k0 += 64) {
        __syncthreads();
#pragma unroll
        for (int j = 0; j < 4; ++j) {
            int row = wid * 32 + j * 8 + (l >> 3);
            int slot = (l & 7) ^ (row & 7);
            gload16(Ap + (size_t)(m0 + row) * DD + k0 + slot * 8,
                    AsB + (wid * 32 + j * 8) * 128);
            gload16(Bp + (size_t)(n0 + row) * DD + k0 + slot * 8,
                    BsB + (wid * 32 + j * 8) * 128);
        }
        __syncthreads();
#pragma unroll
        for (int ks = 0; ks < 2; ++ks) {
            half8 af[4];
#pragma unroll
            for (int mt = 0; mt < 4; ++mt) {
                int row = wm * 64 + mt * 16 + c;
                af[mt] = *(const half8*)(AsB + row * 128 +
                         ((ks * 64 + g * 16) ^ ((row & 7) << 4)));
            }
#pragma unroll
            for (int nt = 0; nt < 4; ++nt) {
                int row = wn * 64 + nt * 16 + c;
                half8 bf = *(const half8*)(BsB + row * 128 +
                           ((ks * 64 + g * 16) ^ ((row & 7) << 4)));
#pragma unroll
                for (int mt = 0; mt < 4; ++mt)
                    acc[mt][nt] = __builtin_amdgcn_mfma_f32_16x16x32_f16(
                        af[mt], bf, acc[mt][nt], 0, 0, 0);
            }
        }
    }

    const float post = (gz == 0) ? 0.125f * LOG2E : 1.0f;
    if (gz < 2) {
        f16* dst = gz ? Ko : Qo;
#pragma unroll
        for (int nt = 0; nt < 4; ++nt) {
            int n = n0 + wn * 64 + nt * 16 + c;
            float bn = bias[n];
            int h = n >> 6, hd = n & 63;
#pragma unroll
            for (int mt = 0; mt < 4; ++mt)
#pragma unroll
                for (int reg = 0; reg < 4; ++reg) {
                    int m = m0 + wm * 64 + mt * 16 + 4 * g + reg;
                    int b = m >> 11, s = m & (SS - 1);
                    dst[(((size_t)(b * HH + h)) * SS + s) * 64 + hd] =
                        (f16)((acc[mt][nt][reg] + bn) * post);
                }
        }
    } else {
#pragma unroll
        for (int mt = 0; mt < 4; ++mt)
#pragma unroll
            for (int reg = 0; reg < 4; ++reg) {
                int m = m0 + wm * 64 + mt * 16 + 4 * g + reg;   // d index
                float bd = bias[m];
                int h = m >> 6, dl = m & 63;
#pragma unroll
                for (int nt = 0; nt < 4; ++nt) {
                    int n = n0 + wn * 64 + nt * 16 + c;          // s index
                    int b = n >> 11, s = n & (SS - 1);
                    VTo[(((size_t)(b * HH + h)) * 64 + dl) * SS + s] =
                        (f16)(acc[mt][nt][reg] + bd);
                }
            }
    }
}

// ============================================================
// Flash attention v4: swapped QK^T, lane-local softmax, in-register P;
// QBLK=128 (two 64-row q-strips share each staged K/V tile: every
// K-fragment LDS read feeds 2 MFMAs, every V read feeds 4).
// K/V double-buffered reg-staging, one barrier/iter. LDS 32 KB.
// grid (q-tiles=16, bh=32) so same-bh blocks are dispatch-adjacent.
// ============================================================
__global__ __launch_bounds__(256, 2)
void attn_fwd(const f16* __restrict__ Qw, const f16* __restrict__ Kw,
              const f16* __restrict__ VTw, const f16* __restrict__ rpbT,
              const u64* __restrict__ mbits, f16* __restrict__ AOh)
{
    __shared__ f16 Ks[2][64 * 64];
    __shared__ f16 Vs[2][64 * 64];

    const int t = threadIdx.x, wid = t >> 6, l = t & 63, c = l & 15, g = l >> 4;
    const int bh = blockIdx.y, b = bh >> 4, h = bh & 15;
    const int q0 = blockIdx.x * 128;
    const size_t baseSD = (size_t)bh * SS * 64;
    const size_t baseDS = (size_t)bh * 64 * SS;
    const f16* Kbase = Kw + baseSD;
    const f16* Vbase = VTw + baseDS;

    const int qrowA = q0 + wid * 16 + c;             // strip A softmax row
    const int qrowB = qrowA + 64;                    // strip B
    const f16* bpA = rpbT + (size_t)h * SS * SS + (size_t)qrowA * SS + g * 16;
    const f16* bpB = bpA + (size_t)64 * SS;
    const u64* mpA = mbits + ((size_t)b * SS + qrowA) * 32;
    const u64* mpB = mpA + 64 * 32;

    // staging geometry (per thread: rows srow0, srow0+8; 16B K chunk,
    // V split into 2 permuted half4 chunks)
    const int s     = l & 7;
    const int srow0 = wid * 16 + (l >> 3);
    const int sswz  = (srow0 & 7) << 4;
    const int kdst  = (s << 4) ^ sswz;               // K byte offset in row
    const int velo  = 32 * (s >> 2) + 16 * (s & 1) + 4 * ((s >> 1) & 1);
    const int vdlo  = (velo * 2) ^ sswz;             // V low half4 byte offset
    const int vdhi  = (velo * 2 + 16) ^ sswz;        // V high half4 byte offset

    // bpermute byte-addresses for gathering per-output-row scalars
    int ga[4];
#pragma unroll
    for (int r = 0; r < 4; ++r) ga[r] = (g * 4 + r) * 4;

    // Q fragments (B-operand layout), both strips
    half8 qfA[2], qfB[2];
    qfA[0] = *(const half8*)(Qw + baseSD + (size_t)qrowA * 64 + g * 8);
    qfA[1] = *(const half8*)(Qw + baseSD + (size_t)qrowA * 64 + 32 + g * 8);
    qfB[0] = *(const half8*)(Qw + baseSD + (size_t)qrowB * 64 + g * 8);
    qfB[1] = *(const half8*)(Qw + baseSD + (size_t)qrowB * 64 + 32 + g * 8);

    // ---- prologue: stage tile 0 ----
    {
        half8 k0 = *(const half8*)(Kbase + (size_t)srow0 * 64 + s * 8);
        half8 k1 = *(const half8*)(Kbase + (size_t)(srow0 + 8) * 64 + s * 8);
        half8 v0 = *(const half8*)(Vbase + (size_t)srow0 * SS + s * 8);
        half8 v1 = *(const half8*)(Vbase + (size_t)(srow0 + 8) * SS + s * 8);
        char* kd = (char*)Ks[0]; char* vd = (char*)Vs[0];
        *(half8*)(kd + srow0 * 128 + kdst) = k0;
        *(half8*)(kd + (srow0 + 8) * 128 + kdst) = k1;
        half4 lo0 = {v0[0], v0[1], v0[2], v0[3]}, hi0 = {v0[4], v0[5], v0[6], v0[7]};
        half4 lo1 = {v1[0], v1[1], v1[2], v1[3]}, hi1 = {v1[4], v1[5], v1[6], v1[7]};
        *(half4*)(vd + srow0 * 128 + vdlo) = lo0;
        *(half4*)(vd + srow0 * 128 + vdhi) = hi0;
        *(half4*)(vd + (srow0 + 8) * 128 + vdlo) = lo1;
        *(half4*)(vd + (srow0 + 8) * 128 + vdhi) = hi1;
    }
    half8 bbA0 = *(const half8*)(bpA);
    half8 bbA1 = *(const half8*)(bpA + 8);
    half8 bbB0 = *(const half8*)(bpB);
    half8 bbB1 = *(const half8*)(bpB + 8);
    u64 mmA = mpA[0], mmB = mpB[0];
    __syncthreads();

    f32x4 accA[4] = {}, accB[4] = {};
    float mrowA = -INFINITY, lpA = 0.f;
    float mrowB = -INFINITY, lpB = 0.f;
    const int shg = 4 * g;

    int buf = 0;
    for (int kt = 0; kt < SS / 64; ++kt) {
        const bool more = (kt + 1 < SS / 64);
        const int jn = more ? (kt + 1) * 64 : 0;     // clamped (safe re-read)
        const int ktn = more ? kt + 1 : 0;

        // ---- issue next-tile loads (registers; hidden under compute)
        half8 k0n = *(const half8*)(Kbase + (size_t)(jn + srow0) * 64 + s * 8);
        half8 k1n = *(const half8*)(Kbase + (size_t)(jn + srow0 + 8) * 64 + s * 8);
        half8 v0n = *(const half8*)(Vbase + (size_t)srow0 * SS + jn + s * 8);
        half8 v1n = *(const half8*)(Vbase + (size_t)(srow0 + 8) * SS + jn + s * 8);
        half8 bbnA0 = *(const half8*)(bpA + jn);
        half8 bbnA1 = *(const half8*)(bpA + jn + 8);
        half8 bbnB0 = *(const half8*)(bpB + jn);
        half8 bbnB1 = *(const half8*)(bpB + jn + 8);
        u64 mmnA = mpA[ktn], mmnB = mpB[ktn];

        char* KsB = (char*)Ks[buf];
        char* VsB = (char*)Vs[buf];

        // ---- C-init: sc = mask ? bias : MASKNEG  (log2-domain)
        u64 shA = mmA >> shg, shB = mmB >> shg;
        f32x4 scA[4], scB[4];
#pragma unroll
        for (int nt = 0; nt < 4; ++nt)
#pragma unroll
            for (int r = 0; r < 4; ++r) {
                float bfA = (float)(nt < 2 ? bbA0[nt * 4 + r] : bbA1[(nt - 2) * 4 + r]);
                float bfB = (float)(nt < 2 ? bbB0[nt * 4 + r] : bbB1[(nt - 2) * 4 + r]);
                scA[nt][r] = ((shA >> (16 * nt + r)) & 1) ? bfA : MASKNEG;
                scB[nt][r] = ((shB >> (16 * nt + r)) & 1) ? bfB : MASKNEG;
            }

        // ---- QK^T swapped: each kf read feeds both strips
        __builtin_amdgcn_s_setprio(1);
#pragma unroll
        for (int ks = 0; ks < 2; ++ks)
#pragma unroll
            for (int nt = 0; nt < 4; ++nt) {
                int row = nt * 16 + c;
                half8 kf = *(const half8*)(KsB + row * 128 +
                           ((ks * 64 + g * 16) ^ ((row & 7) << 4)));
                scA[nt] = __builtin_amdgcn_mfma_f32_16x16x32_f16(
                    kf, qfA[ks], scA[nt], 0, 0, 0);
                scB[nt] = __builtin_amdgcn_mfma_f32_16x16x32_f16(
                    kf, qfB[ks], scB[nt], 0, 0, 0);
            }
        __builtin_amdgcn_s_setprio(0);

        // ---- lane-local softmax (base 2) with defer-max, strip A
        half4 paA[4], paB[4];
        {
            float rm = fmaxf(fmaxf(fmaxf(scA[0][0], scA[0][1]), fmaxf(scA[0][2], scA[0][3])),
                             fmaxf(fmaxf(scA[1][0], scA[1][1]), fmaxf(scA[1][2], scA[1][3])));
            rm = fmaxf(rm, fmaxf(fmaxf(fmaxf(scA[2][0], scA[2][1]), fmaxf(scA[2][2], scA[2][3])),
                                 fmaxf(fmaxf(scA[3][0], scA[3][1]), fmaxf(scA[3][2], scA[3][3]))));
            rm = fmaxf(rm, __shfl_xor(rm, 16));
            rm = fmaxf(rm, __shfl_xor(rm, 32));
            if (!__all(rm <= mrowA + 8.0f)) {
                float mn = fmaxf(mrowA, rm);
                float scal = exp2f(mrowA - mn);
                mrowA = mn;
                lpA *= scal;
                float sq[4];
#pragma unroll
                for (int r = 0; r < 4; ++r)
                    sq[r] = __int_as_float(__builtin_amdgcn_ds_bpermute(
                                ga[r], __float_as_int(scal)));
#pragma unroll
                for (int nt = 0; nt < 4; ++nt)
#pragma unroll
                    for (int r = 0; r < 4; ++r) accA[nt][r] *= sq[r];
            }
            float psum = 0.f;
#pragma unroll
            for (int nt = 0; nt < 4; ++nt)
#pragma unroll
                for (int r = 0; r < 4; ++r) {
                    float p = exp2f(scA[nt][r] - mrowA);
                    scA[nt][r] = p;
                    psum += p;
                }
            lpA += psum;
#pragma unroll
            for (int kk = 0; kk < 4; ++kk) {
                half4 pv = {(f16)scA[kk][0], (f16)scA[kk][1],
                            (f16)scA[kk][2], (f16)scA[kk][3]};
                paA[kk] = pv;
            }
        }
        // ---- strip B
        {
            float rm = fmaxf(fmaxf(fmaxf(scB[0][0], scB[0][1]), fmaxf(scB[0][2], scB[0][3])),
                             fmaxf(fmaxf(scB[1][0], scB[1][1]), fmaxf(scB[1][2], scB[1][3])));
            rm = fmaxf(rm, fmaxf(fmaxf(fmaxf(scB[2][0], scB[2][1]), fmaxf(scB[2][2], scB[2][3])),
                                 fmaxf(fmaxf(scB[3][0], scB[3][1]), fmaxf(scB[3][2], scB[3][3]))));
            rm = fmaxf(rm, __shfl_xor(rm, 16));
            rm = fmaxf(rm, __shfl_xor(rm, 32));
            if (!__all(rm <= mrowB + 8.0f)) {
                float mn = fmaxf(mrowB, rm);
                float scal = exp2f(mrowB - mn);
                mrowB = mn;
                lpB *= scal;
                float sq[4];
#pragma unroll
                for (int r = 0; r < 4; ++r)
                    sq[r] = __int_as_float(__builtin_amdgcn_ds_bpermute(
                                ga[r], __float_as_int(scal)));
#pragma unroll
                for (int nt = 0; nt < 4; ++nt)
#pragma unroll
                    for (int r = 0; r < 4; ++r) accB[nt][r] *= sq[r];
            }
            float psum = 0.f;
#pragma unroll
            for (int nt = 0; nt < 4; ++nt)
#pragma unroll
                for (int r = 0; r < 4; ++r) {
                    float p = exp2f(scB[nt][r] - mrowB);
                    scB[nt][r] = p;
                    psum += p;
                }
            lpB += psum;
#pragma unroll
            for (int kk = 0; kk < 4; ++kk) {
                half4 pv = {(f16)scB[kk][0], (f16)scB[kk][1],
                            (f16)scB[kk][2], (f16)scB[kk][3]};
                paB[kk] = pv;
            }
        }

        // ---- PV: each vf read feeds 4 MFMAs (2 per strip)
        __builtin_amdgcn_s_setprio(1);
#pragma unroll
        for (int ks = 0; ks < 2; ++ks)
#pragma unroll
            for (int nt2 = 0; nt2 < 4; ++nt2) {
                int row = nt2 * 16 + c;
                half8 vf = *(const half8*)(VsB + row * 128 +
                           ((ks * 64 + g * 16) ^ ((row & 7) << 4)));
                half4 vlo = {vf[0], vf[1], vf[2], vf[3]};
                half4 vhi = {vf[4], vf[5], vf[6], vf[7]};
                accA[nt2] = __builtin_amdgcn_mfma_f32_16x16x16f16(
                    paA[2 * ks], vlo, accA[nt2], 0, 0, 0);
                accA[nt2] = __builtin_amdgcn_mfma_f32_16x16x16f16(
                    paA[2 * ks + 1], vhi, accA[nt2], 0, 0, 0);
                accB[nt2] = __builtin_amdgcn_mfma_f32_16x16x16f16(
                    paB[2 * ks], vlo, accB[nt2], 0, 0, 0);
                accB[nt2] = __builtin_amdgcn_mfma_f32_16x16x16f16(
                    paB[2 * ks + 1], vhi, accB[nt2], 0, 0, 0);
            }
        __builtin_amdgcn_s_setprio(0);

        // ---- commit next tile: regs -> LDS buf^1 (vmcnt wait lands here)
        if (more) {
            char* kd = (char*)Ks[buf ^ 1];
            char* vd = (char*)Vs[buf ^ 1];
            *(half8*)(kd + srow0 * 128 + kdst) = k0n;
            *(half8*)(kd + (srow0 + 8) * 128 + kdst) = k1n;
            half4 lo0 = {v0n[0], v0n[1], v0n[2], v0n[3]}, hi0 = {v0n[4], v0n[5], v0n[6], v0n[7]};
            half4 lo1 = {v1n[0], v1n[1], v1n[2], v1n[3]}, hi1 = {v1n[4], v1n[5], v1n[6], v1n[7]};
            *(half4*)(vd + srow0 * 128 + vdlo) = lo0;
            *(half4*)(vd + srow0 * 128 + vdhi) = hi0;
            *(half4*)(vd + (srow0 + 8) * 128 + vdlo) = lo1;
            *(half4*)(vd + (srow0 + 8) * 128 + vdhi) = hi1;
            buf ^= 1;
            bbA0 = bbnA0; bbA1 = bbnA1; bbB0 = bbnB0; bbB1 = bbnB1;
            mmA = mmnA; mmB = mmnB;
        }
        __syncthreads();   // one barrier per iteration
    }

    // ---- epilogue: per-strip cross-g sums, gather inverses, store
    {
        float lt = lpA;
        lt += __shfl_xor(lt, 16);
        lt += __shfl_xor(lt, 32);
        float linv[4];
#pragma unroll
        for (int r = 0; r < 4; ++r)
            linv[r] = 1.0f / __int_as_float(__builtin_amdgcn_ds_bpermute(
                          ga[r], __float_as_int(lt)));
#pragma unroll
        for (int r = 0; r < 4; ++r) {
            int qrow = q0 + wid * 16 + 4 * g + r;
#pragma unroll
            for (int nt2 = 0; nt2 < 4; ++nt2)
                AOh[((size_t)b * SS + qrow) * DD + h * 64 + nt2 * 16 + c] =
                    (f16)(accA[nt2][r] * linv[r]);
        }
    }
    {
        float lt = lpB;
        lt += __shfl_xor(lt, 16);
        lt += __shfl_xor(lt, 32);
        float linv[4];
#pragma unroll
        for (int r = 0; r < 4; ++r)
            linv[r] = 1.0f / __int_as_float(__builtin_amdgcn_ds_bpermute(
                          ga[r], __float_as_int(lt)));
#pragma unroll
        for (int r = 0; r < 4; ++r) {
            int qrow = q0 + 64 + wid * 16 + 4 * g + r;
#pragma unroll
            for (int nt2 = 0; nt2 < 4; ++nt2)
                AOh[((size_t)b * SS + qrow) * DD + h * 64 + nt2 * 16 + c] =
                    (f16)(accB[nt2][r] * linv[r]);
        }
    }
}

// ============================================================
// Output projection: out(f32) = AO(f16) @ Wo + bo.
// ============================================================
__global__ __launch_bounds__(256)
void gemm_out(const f16* __restrict__ A, const f16* __restrict__ BT,
              const float* __restrict__ bias, float* __restrict__ out)
{
    __shared__ f16 As[128 * 64];
    __shared__ f16 Bs[128 * 64];
    const int t = threadIdx.x, wid = t >> 6, l = t & 63, c = l & 15, g = l >> 4;
    const int m0 = blockIdx.y * 128, n0 = blockIdx.x * 128;
    const int wm = wid >> 1, wn = wid & 1;
    f32x4 acc[4][4] = {};
    char* AsB = (char*)As; char* BsB = (char*)Bs;

    for (int k0 = 0; k0 < DD; k0 += 64) {
        __syncthreads();
#pragma unroll
        for (int j = 0; j < 4; ++j) {
            int row = wid * 32 + j * 8 + (l >> 3);
            int slot = (l & 7) ^ (row & 7);
            gload16(A + (size_t)(m0 + row) * DD + k0 + slot * 8,
                    AsB + (wid * 32 + j * 8) * 128);
            gload16(BT + (size_t)(n0 + row) * DD + k0 + slot * 8,
                    BsB + (wid * 32 + j * 8) * 128);
        }
        __syncthreads();
#pragma unroll
        for (int ks = 0; ks < 2; ++ks) {
            half8 af[4];
#pragma unroll
            for (int mt = 0; mt < 4; ++mt) {
                int row = wm * 64 + mt * 16 + c;
                af[mt] = *(const half8*)(AsB + row * 128 +
                         ((ks * 64 + g * 16) ^ ((row & 7) << 4)));
            }
#pragma unroll
            for (int nt = 0; nt < 4; ++nt) {
                int row = wn * 64 + nt * 16 + c;
                half8 bf = *(const half8*)(BsB + row * 128 +
                           ((ks * 64 + g * 16) ^ ((row & 7) << 4)));
#pragma unroll
                for (int mt = 0; mt < 4; ++mt)
                    acc[mt][nt] = __builtin_amdgcn_mfma_f32_16x16x32_f16(
                        af[mt], bf, acc[mt][nt], 0, 0, 0);
            }
        }
    }
#pragma unroll
    for (int nt = 0; nt < 4; ++nt) {
        int n = n0 + wn * 64 + nt * 16 + c;
        float bn = bias[n];
#pragma unroll
        for (int mt = 0; mt < 4; ++mt)
#pragma unroll
            for (int reg = 0; reg < 4; ++reg) {
                int m = m0 + wm * 64 + mt * 16 + 4 * g + reg;
                out[(size_t)m * DD + n] = acc[mt][nt][reg] + bn;
            }
    }
}

extern "C" void kernel_launch(void* const* d_in, const int* in_sizes, int n_in,
                              void* d_out, int out_size, void* d_ws, size_t ws_size,
                              hipStream_t stream)
{
    (void)in_sizes; (void)n_in; (void)out_size; (void)ws_size;

    const float* query = (const float*)d_in[0];
    const float* key   = (const float*)d_in[1];
    const float* value = (const float*)d_in[2];
    const int*   mask  = (const int*)d_in[3];
    const float* rpb   = (const float*)d_in[4];
    const float* Wq = (const float*)d_in[5];  const float* bq = (const float*)d_in[6];
    const float* Wk = (const float*)d_in[7];  const float* bk = (const float*)d_in[8];
    const float* Wv = (const float*)d_in[9];  const float* bv = (const float*)d_in[10];
    const float* Wo = (const float*)d_in[11]; const float* bo = (const float*)d_in[12];
    float* out = (float*)d_out;

    // workspace layout (f16 elements). AOh aliases Xq (dead after proj3).
    const size_t NX = (size_t)2 * SS * DD;   // 4096x1024
    const size_t NW = (size_t)DD * DD;       // 1024x1024
    f16* Xq    = (f16*)d_ws;
    f16* Xk    = Xq + NX;
    f16* Xv    = Xk + NX;
    f16* WqT   = Xv + NX;
    f16* WkT   = WqT + NW;
    f16* WvT   = WkT + NW;
    f16* WoT   = WvT + NW;
    f16* Qw    = WoT + NW;
    f16* Kw    = Qw + NX;
    f16* VTw   = Kw + NX;
    f16* rpbT  = VTw + NX;                   // 16*2048*2048 f16 = 128 MB
    u64* mbits = (u64*)(rpbT + (size_t)HH * SS * SS);  // 1 MB
    f16* AOh   = Xq;   // alias

    cvt_x<<<dim3(NX / 2048, 1, 3), 256, 0, stream>>>(query, key, value, Xq, Xk, Xv);
    cvt_wT<<<dim3(16, 16, 4), 256, 0, stream>>>(Wq, Wk, Wv, Wo, WqT, WkT, WvT, WoT);
    cvt_rpbT3<<<dim3(SS / 16, SS / 64), 256, 0, stream>>>(rpb, rpbT);
    cvt_maskbits<<<dim3((2 * SS) / 4), 256, 0, stream>>>(mask, mbits);
    proj3<<<dim3(8, 32, 3), 256, 0, stream>>>(Xq, Xk, Xv, WqT, WkT, WvT,
                                              bq, bk, bv, Qw, Kw, VTw);
    attn_fwd<<<dim3(SS / 128, 2 * HH), 256, 0, stream>>>(Qw, Kw, VTw, rpbT, mbits, AOh);
    gemm_out<<<dim3(8, 32), 256, 0, stream>>>(AOh, WoT, bo, out);
}

// Round 10
// 280.834 us; speedup vs baseline: 1.0787x; 1.0787x over previous
//
#include <hip/hip_runtime.h>
#include <math.h>

#define SS 2048
#define DD 1024
#define HH 16

typedef _Float16 f16;
typedef _Float16 half8 __attribute__((ext_vector_type(8)));
typedef _Float16 half4 __attribute__((ext_vector_type(4)));
typedef float f32x4 __attribute__((ext_vector_type(4)));
typedef unsigned long long u64;

#define LOG2E 1.44269504f
#define MASKNEG -30000.0f

__device__ __forceinline__ void gload16(const void* g, void* lds) {
    __builtin_amdgcn_global_load_lds(
        (const __attribute__((address_space(1))) unsigned int*)g,
        (__attribute__((address_space(3))) unsigned int*)lds, 16, 0, 0);
}

// ============================================================
// fused prep A: cvt_x (q/k/v f32->f16, 6144 blocks) + cvt_wT
// (weight transpose+cast, 1024 blocks). Independent work, one launch.
// ============================================================
__global__ __launch_bounds__(256)
void prep_xw(const float* __restrict__ q, const float* __restrict__ k,
             const float* __restrict__ v, f16* __restrict__ oq,
             f16* __restrict__ ok, f16* __restrict__ ov,
             const float* __restrict__ wq, const float* __restrict__ wk,
             const float* __restrict__ wv, const float* __restrict__ wo,
             f16* __restrict__ owq, f16* __restrict__ owk,
             f16* __restrict__ owv, f16* __restrict__ owo)
{
    __shared__ __align__(16) char smem[16640];
    const int bid = blockIdx.x;
    const int t = threadIdx.x;
    if (bid < 6144) {
        const int z = bid / 2048, bx = bid % 2048;
        const float* src = z == 0 ? q : z == 1 ? k : v;
        f16* dst = z == 0 ? oq : z == 1 ? ok : ov;
        size_t i = ((size_t)bx * 256 + t) * 8;
        float4 v0 = *reinterpret_cast<const float4*>(src + i);
        float4 v1 = *reinterpret_cast<const float4*>(src + i + 4);
        half8 h;
        h[0] = (f16)v0.x; h[1] = (f16)v0.y; h[2] = (f16)v0.z; h[3] = (f16)v0.w;
        h[4] = (f16)v1.x; h[5] = (f16)v1.y; h[6] = (f16)v1.z; h[7] = (f16)v1.w;
        *reinterpret_cast<half8*>(dst + i) = h;
    } else {
        const int r = bid - 6144;
        const int z = r / 256;
        const int bx = r % 16, by = (r / 16) % 16;
        const float* W = z == 0 ? wq : z == 1 ? wk : z == 2 ? wv : wo;
        f16* WT = z == 0 ? owq : z == 1 ? owk : z == 2 ? owv : owo;
        float (*Lt)[65] = (float (*)[65])smem;
        const int n0 = bx * 64, k0 = by * 64;
        {
            int row = t >> 2;
            int c0  = (t & 3) * 16;
#pragma unroll
            for (int u = 0; u < 4; ++u) {
                float4 x = *reinterpret_cast<const float4*>(
                    &W[(size_t)(k0 + row) * DD + n0 + c0 + u * 4]);
                Lt[row][c0 + u * 4 + 0] = x.x;
                Lt[row][c0 + u * 4 + 1] = x.y;
                Lt[row][c0 + u * 4 + 2] = x.z;
                Lt[row][c0 + u * 4 + 3] = x.w;
            }
        }
        __syncthreads();
        {
            int n  = t >> 2;
            int kc = (t & 3) * 16;
            half8 h0, h1;
#pragma unroll
            for (int u = 0; u < 8; ++u) h0[u] = (f16)Lt[kc + u][n];
#pragma unroll
            for (int u = 0; u < 8; ++u) h1[u] = (f16)Lt[kc + 8 + u][n];
            f16* dst = &WT[(size_t)(n0 + n) * DD + k0 + kc];
            *reinterpret_cast<half8*>(dst) = h0;
            *reinterpret_cast<half8*>(dst + 8) = h1;
        }
    }
}

// ============================================================
// fused prep B bodies: proj3 / rpbT3 / maskbits
// ============================================================
__device__ void proj3_body(char* smem, int gx, int gy, int gz,
                           const f16* Xq, const f16* Xk, const f16* Xv,
                           const f16* WqT, const f16* WkT, const f16* WvT,
                           const float* bq, const float* bk, const float* bv,
                           f16* Qo, f16* Ko, f16* VTo)
{
    char* AsB = smem;
    char* BsB = smem + 128 * 64 * 2;
    const int t = threadIdx.x, wid = t >> 6, l = t & 63, c = l & 15, g = l >> 4;
    const f16 *Ap, *Bp; const float* bias; int m0, n0;
    if (gz == 2) { Ap = WvT; Bp = Xv; bias = bv; m0 = gx * 128; n0 = gy * 128; }
    else if (gz == 1) { Ap = Xk; Bp = WkT; bias = bk; m0 = gy * 128; n0 = gx * 128; }
    else { Ap = Xq; Bp = WqT; bias = bq; m0 = gy * 128; n0 = gx * 128; }
    const int wm = wid >> 1, wn = wid & 1;
    f32x4 acc[4][4] = {};

    for (int k0 = 0; k0 < DD; k0 += 64) {
        __syncthreads();
#pragma unroll
        for (int j = 0; j < 4; ++j) {
            int row = wid * 32 + j * 8 + (l >> 3);
            int slot = (l & 7) ^ (row & 7);
            gload16(Ap + (size_t)(m0 + row) * DD + k0 + slot * 8,
                    AsB + (wid * 32 + j * 8) * 128);
            gload16(Bp + (size_t)(n0 + row) * DD + k0 + slot * 8,
                    BsB + (wid * 32 + j * 8) * 128);
        }
        __syncthreads();
#pragma unroll
        for (int ks = 0; ks < 2; ++ks) {
            half8 af[4];
#pragma unroll
            for (int mt = 0; mt < 4; ++mt) {
                int row = wm * 64 + mt * 16 + c;
                af[mt] = *(const half8*)(AsB + row * 128 +
                         ((ks * 64 + g * 16) ^ ((row & 7) << 4)));
            }
#pragma unroll
            for (int nt = 0; nt < 4; ++nt) {
                int row = wn * 64 + nt * 16 + c;
                half8 bf = *(const half8*)(BsB + row * 128 +
                           ((ks * 64 + g * 16) ^ ((row & 7) << 4)));
#pragma unroll
                for (int mt = 0; mt < 4; ++mt)
                    acc[mt][nt] = __builtin_amdgcn_mfma_f32_16x16x32_f16(
                        af[mt], bf, acc[mt][nt], 0, 0, 0);
            }
        }
    }

    const float post = (gz == 0) ? 0.125f * LOG2E : 1.0f;
    if (gz < 2) {
        f16* dst = gz ? Ko : Qo;
#pragma unroll
        for (int nt = 0; nt < 4; ++nt) {
            int n = n0 + wn * 64 + nt * 16 + c;
            float bn = bias[n];
            int h = n >> 6, hd = n & 63;
#pragma unroll
            for (int mt = 0; mt < 4; ++mt)
#pragma unroll
                for (int reg = 0; reg < 4; ++reg) {
                    int m = m0 + wm * 64 + mt * 16 + 4 * g + reg;
                    int b = m >> 11, s = m & (SS - 1);
                    dst[(((size_t)(b * HH + h)) * SS + s) * 64 + hd] =
                        (f16)((acc[mt][nt][reg] + bn) * post);
                }
        }
    } else {
#pragma unroll
        for (int mt = 0; mt < 4; ++mt)
#pragma unroll
            for (int reg = 0; reg < 4; ++reg) {
                int m = m0 + wm * 64 + mt * 16 + 4 * g + reg;   // d index
                float bd = bias[m];
                int h = m >> 6, dl = m & 63;
#pragma unroll
                for (int nt = 0; nt < 4; ++nt) {
                    int n = n0 + wn * 64 + nt * 16 + c;          // s index
                    int b = n >> 11, s = n & (SS - 1);
                    VTo[(((size_t)(b * HH + h)) * 64 + dl) * SS + s] =
                        (f16)(acc[mt][nt][reg] + bd);
                }
            }
    }
}

__device__ void rpbT3_body(char* smem, int gx, int gy,
                           const float* rpb, f16* rpbT)
{
    // Lt[h][i][j-local] with +2 pad: [16][16][66] f16
    f16 (*Lt)[16][66] = (f16 (*)[16][66])smem;
    const int t = threadIdx.x, wid = t >> 6, l = t & 63;
    const int i0 = gx * 16;
    const int j0 = gy * 64;
    const int il = l >> 2;
    const int h0 = (l & 3) * 4;
#pragma unroll
    for (int p = 0; p < 16; ++p) {
        int jl = p * 4 + wid;
        float4 v = *reinterpret_cast<const float4*>(
            rpb + ((size_t)(j0 + jl) * SS + i0 + il) * HH + h0);
        Lt[h0 + 0][il][jl] = (f16)(v.x * LOG2E);
        Lt[h0 + 1][il][jl] = (f16)(v.y * LOG2E);
        Lt[h0 + 2][il][jl] = (f16)(v.z * LOG2E);
        Lt[h0 + 3][il][jl] = (f16)(v.w * LOG2E);
    }
    __syncthreads();
    const int part = t & 7;
#pragma unroll
    for (int p = 0; p < 8; ++p) {
        int rowid = p * 32 + (t >> 3);
        int h = rowid >> 4, i2 = rowid & 15;
        half8 v;
#pragma unroll
        for (int e = 0; e < 8; ++e) {
            // out position q = part*8+e = g*16+nt*4+reg -> source j
            int sig = 32 * (part & 1) + 16 * (e >> 2) + 4 * (part >> 1) + (e & 3);
            v[e] = Lt[h][i2][sig];
        }
        *reinterpret_cast<half8*>(
            rpbT + ((size_t)h * SS + i0 + i2) * SS + j0 + part * 8) = v;
    }
}

__device__ void maskbits_body(int gx, const int* mask, u64* mb)
{
    const int t = threadIdx.x, wid = t >> 6, l = t & 63;
    const int row = gx * 4 + wid;     // b*SS+i
    const int* src = mask + (size_t)row * SS;
    u64* dst = mb + (size_t)row * 32;
    for (int it = 0; it < 32; ++it) {
        int mv = src[it * 64 + l];
        u64 bal = __ballot(mv != 0);
        if (l == 0) dst[it] = bal;
    }
}

// fused prep B: proj3 (768) + rpbT3 (4096) + maskbits (1024) = 5888 blocks.
// Compute-bound proj3 blocks co-reside with BW-bound transpose blocks,
// overlapping MFMA with HBM streaming in one launch.
__global__ __launch_bounds__(256)
void prep_big(const f16* __restrict__ Xq, const f16* __restrict__ Xk,
              const f16* __restrict__ Xv, const f16* __restrict__ WqT,
              const f16* __restrict__ WkT, const f16* __restrict__ WvT,
              const float* __restrict__ bq, const float* __restrict__ bk,
              const float* __restrict__ bv,
              f16* __restrict__ Qo, f16* __restrict__ Ko, f16* __restrict__ VTo,
              const float* __restrict__ rpb, f16* __restrict__ rpbT,
              const int* __restrict__ mask, u64* __restrict__ mbits)
{
    __shared__ __align__(16) char smem[33792];
    const int bid = blockIdx.x;
    if (bid < 768) {
        proj3_body(smem, bid % 8, (bid / 8) % 32, bid / 256,
                   Xq, Xk, Xv, WqT, WkT, WvT, bq, bk, bv, Qo, Ko, VTo);
    } else if (bid < 768 + 4096) {
        const int r = bid - 768;
        rpbT3_body(smem, r % 128, r / 128, rpb, rpbT);
    } else {
        maskbits_body(bid - (768 + 4096), mask, mbits);
    }
}

// ============================================================
// Flash attention (R8 version): swapped QK^T, lane-local softmax,
// in-register P, QBLK=64, 4 blocks/CU, one barrier/iter. LDS 32 KB.
// ============================================================
__global__ __launch_bounds__(256, 4)
void attn_fwd(const f16* __restrict__ Qw, const f16* __restrict__ Kw,
              const f16* __restrict__ VTw, const f16* __restrict__ rpbT,
              const u64* __restrict__ mbits, f16* __restrict__ AOh)
{
    __shared__ f16 Ks[2][64 * 64];
    __shared__ f16 Vs[2][64 * 64];

    const int t = threadIdx.x, wid = t >> 6, l = t & 63, c = l & 15, g = l >> 4;
    const int bh = blockIdx.x, b = bh >> 4, h = bh & 15;
    const int q0 = blockIdx.y * 64;
    const size_t baseSD = (size_t)bh * SS * 64;
    const size_t baseDS = (size_t)bh * 64 * SS;
    const f16* Kbase = Kw + baseSD;
    const f16* Vbase = VTw + baseDS;

    const int qrow_c = q0 + wid * 16 + c;            // this lane's softmax row
    const f16* bp = rpbT + (size_t)h * SS * SS + (size_t)qrow_c * SS + g * 16;
    const u64* mp = mbits + ((size_t)b * SS + qrow_c) * 32;

    const int s     = l & 7;
    const int srow0 = wid * 16 + (l >> 3);
    const int sswz  = (srow0 & 7) << 4;
    const int kdst  = (s << 4) ^ sswz;
    const int velo  = 32 * (s >> 2) + 16 * (s & 1) + 4 * ((s >> 1) & 1);
    const int vdlo  = (velo * 2) ^ sswz;
    const int vdhi  = (velo * 2 + 16) ^ sswz;

    int ga[4];
#pragma unroll
    for (int r = 0; r < 4; ++r) ga[r] = (g * 4 + r) * 4;

    half8 qf[2];
    qf[0] = *(const half8*)(Qw + baseSD + (size_t)qrow_c * 64 + g * 8);
    qf[1] = *(const half8*)(Qw + baseSD + (size_t)qrow_c * 64 + 32 + g * 8);

    // ---- prologue: stage tile 0 ----
    {
        half8 k0 = *(const half8*)(Kbase + (size_t)srow0 * 64 + s * 8);
        half8 k1 = *(const half8*)(Kbase + (size_t)(srow0 + 8) * 64 + s * 8);
        half8 v0 = *(const half8*)(Vbase + (size_t)srow0 * SS + s * 8);
        half8 v1 = *(const half8*)(Vbase + (size_t)(srow0 + 8) * SS + s * 8);
        char* kd = (char*)Ks[0]; char* vd = (char*)Vs[0];
        *(half8*)(kd + srow0 * 128 + kdst) = k0;
        *(half8*)(kd + (srow0 + 8) * 128 + kdst) = k1;
        half4 lo0 = {v0[0], v0[1], v0[2], v0[3]}, hi0 = {v0[4], v0[5], v0[6], v0[7]};
        half4 lo1 = {v1[0], v1[1], v1[2], v1[3]}, hi1 = {v1[4], v1[5], v1[6], v1[7]};
        *(half4*)(vd + srow0 * 128 + vdlo) = lo0;
        *(half4*)(vd + srow0 * 128 + vdhi) = hi0;
        *(half4*)(vd + (srow0 + 8) * 128 + vdlo) = lo1;
        *(half4*)(vd + (srow0 + 8) * 128 + vdhi) = hi1;
    }
    half8 bb0 = *(const half8*)(bp);
    half8 bb1 = *(const half8*)(bp + 8);
    u64 mm = mp[0];
    __syncthreads();

    f32x4 acc[4] = {};
    float mrow = -INFINITY, lp = 0.f;
    const int shg = 4 * g;

    int buf = 0;
    for (int kt = 0; kt < SS / 64; ++kt) {
        const bool more = (kt + 1 < SS / 64);
        const int jn = more ? (kt + 1) * 64 : 0;
        const int ktn = more ? kt + 1 : 0;

        half8 k0n = *(const half8*)(Kbase + (size_t)(jn + srow0) * 64 + s * 8);
        half8 k1n = *(const half8*)(Kbase + (size_t)(jn + srow0 + 8) * 64 + s * 8);
        half8 v0n = *(const half8*)(Vbase + (size_t)srow0 * SS + jn + s * 8);
        half8 v1n = *(const half8*)(Vbase + (size_t)(srow0 + 8) * SS + jn + s * 8);
        half8 bbn0 = *(const half8*)(bp + jn);
        half8 bbn1 = *(const half8*)(bp + jn + 8);
        u64 mmn = mp[ktn];

        char* KsB = (char*)Ks[buf];
        char* VsB = (char*)Vs[buf];

        // ---- C-init: sc = mask ? bias : MASKNEG  (log2-domain)
        u64 sh = mm >> shg;
        f32x4 sc[4];
#pragma unroll
        for (int nt = 0; nt < 4; ++nt)
#pragma unroll
            for (int r = 0; r < 4; ++r) {
                float bf = (float)(nt < 2 ? bb0[nt * 4 + r] : bb1[(nt - 2) * 4 + r]);
                sc[nt][r] = ((sh >> (16 * nt + r)) & 1) ? bf : MASKNEG;
            }

        // ---- QK^T swapped
        __builtin_amdgcn_s_setprio(1);
#pragma unroll
        for (int ks = 0; ks < 2; ++ks)
#pragma unroll
            for (int nt = 0; nt < 4; ++nt) {
                int row = nt * 16 + c;
                half8 kf = *(const half8*)(KsB + row * 128 +
                           ((ks * 64 + g * 16) ^ ((row & 7) << 4)));
                sc[nt] = __builtin_amdgcn_mfma_f32_16x16x32_f16(
                    kf, qf[ks], sc[nt], 0, 0, 0);
            }
        __builtin_amdgcn_s_setprio(0);

        // ---- lane-local softmax (base 2) with defer-max
        float rm = fmaxf(fmaxf(fmaxf(sc[0][0], sc[0][1]), fmaxf(sc[0][2], sc[0][3])),
                         fmaxf(fmaxf(sc[1][0], sc[1][1]), fmaxf(sc[1][2], sc[1][3])));
        rm = fmaxf(rm, fmaxf(fmaxf(fmaxf(sc[2][0], sc[2][1]), fmaxf(sc[2][2], sc[2][3])),
                             fmaxf(fmaxf(sc[3][0], sc[3][1]), fmaxf(sc[3][2], sc[3][3]))));
        rm = fmaxf(rm, __shfl_xor(rm, 16));
        rm = fmaxf(rm, __shfl_xor(rm, 32));
        if (!__all(rm <= mrow + 8.0f)) {
            float mn = fmaxf(mrow, rm);
            float scal = exp2f(mrow - mn);
            mrow = mn;
            lp *= scal;
            float sq[4];
#pragma unroll
            for (int r = 0; r < 4; ++r)
                sq[r] = __int_as_float(__builtin_amdgcn_ds_bpermute(
                            ga[r], __float_as_int(scal)));
#pragma unroll
            for (int nt = 0; nt < 4; ++nt)
#pragma unroll
                for (int r = 0; r < 4; ++r) acc[nt][r] *= sq[r];
        }
        float psum = 0.f;
#pragma unroll
        for (int nt = 0; nt < 4; ++nt)
#pragma unroll
            for (int r = 0; r < 4; ++r) {
                float p = exp2f(sc[nt][r] - mrow);
                sc[nt][r] = p;
                psum += p;
            }
        lp += psum;

        // ---- pack P in-register
        half4 pa[4];
#pragma unroll
        for (int kk = 0; kk < 4; ++kk) {
            half4 pv = {(f16)sc[kk][0], (f16)sc[kk][1],
                        (f16)sc[kk][2], (f16)sc[kk][3]};
            pa[kk] = pv;
        }

        // ---- PV via 16x16x16, b128 V reads
        __builtin_amdgcn_s_setprio(1);
#pragma unroll
        for (int ks = 0; ks < 2; ++ks)
#pragma unroll
            for (int nt2 = 0; nt2 < 4; ++nt2) {
                int row = nt2 * 16 + c;
                half8 vf = *(const half8*)(VsB + row * 128 +
                           ((ks * 64 + g * 16) ^ ((row & 7) << 4)));
                half4 vlo = {vf[0], vf[1], vf[2], vf[3]};
                half4 vhi = {vf[4], vf[5], vf[6], vf[7]};
                acc[nt2] = __builtin_amdgcn_mfma_f32_16x16x16f16(
                    pa[2 * ks], vlo, acc[nt2], 0, 0, 0);
                acc[nt2] = __builtin_amdgcn_mfma_f32_16x16x16f16(
                    pa[2 * ks + 1], vhi, acc[nt2], 0, 0, 0);
            }
        __builtin_amdgcn_s_setprio(0);

        // ---- commit next tile (vmcnt wait lands here, after compute)
        if (more) {
            char* kd = (char*)Ks[buf ^ 1];
            char* vd = (char*)Vs[buf ^ 1];
            *(half8*)(kd + srow0 * 128 + kdst) = k0n;
            *(half8*)(kd + (srow0 + 8) * 128 + kdst) = k1n;
            half4 lo0 = {v0n[0], v0n[1], v0n[2], v0n[3]}, hi0 = {v0n[4], v0n[5], v0n[6], v0n[7]};
            half4 lo1 = {v1n[0], v1n[1], v1n[2], v1n[3]}, hi1 = {v1n[4], v1n[5], v1n[6], v1n[7]};
            *(half4*)(vd + srow0 * 128 + vdlo) = lo0;
            *(half4*)(vd + srow0 * 128 + vdhi) = hi0;
            *(half4*)(vd + (srow0 + 8) * 128 + vdlo) = lo1;
            *(half4*)(vd + (srow0 + 8) * 128 + vdhi) = hi1;
            buf ^= 1;
            bb0 = bbn0; bb1 = bbn1; mm = mmn;
        }
        __syncthreads();
    }

    // ---- epilogue
    float lt = lp;
    lt += __shfl_xor(lt, 16);
    lt += __shfl_xor(lt, 32);
    float linv[4];
#pragma unroll
    for (int r = 0; r < 4; ++r)
        linv[r] = 1.0f / __int_as_float(__builtin_amdgcn_ds_bpermute(
                      ga[r], __float_as_int(lt)));
#pragma unroll
    for (int r = 0; r < 4; ++r) {
        int qrow = q0 + wid * 16 + 4 * g + r;
#pragma unroll
        for (int nt2 = 0; nt2 < 4; ++nt2)
            AOh[((size_t)b * SS + qrow) * DD + h * 64 + nt2 * 16 + c] =
                (f16)(acc[nt2][r] * linv[r]);
    }
}

// ============================================================
// Output projection: out(f32) = AO(f16) @ Wo + bo.
// ============================================================
__global__ __launch_bounds__(256)
void gemm_out(const f16* __restrict__ A, const f16* __restrict__ BT,
              const float* __restrict__ bias, float* __restrict__ out)
{
    __shared__ f16 As[128 * 64];
    __shared__ f16 Bs[128 * 64];
    const int t = threadIdx.x, wid = t >> 6, l = t & 63, c = l & 15, g = l >> 4;
    const int m0 = blockIdx.y * 128, n0 = blockIdx.x * 128;
    const int wm = wid >> 1, wn = wid & 1;
    f32x4 acc[4][4] = {};
    char* AsB = (char*)As; char* BsB = (char*)Bs;

    for (int k0 = 0; k0 < DD; k0 += 64) {
        __syncthreads();
#pragma unroll
        for (int j = 0; j < 4; ++j) {
            int row = wid * 32 + j * 8 + (l >> 3);
            int slot = (l & 7) ^ (row & 7);
            gload16(A + (size_t)(m0 + row) * DD + k0 + slot * 8,
                    AsB + (wid * 32 + j * 8) * 128);
            gload16(BT + (size_t)(n0 + row) * DD + k0 + slot * 8,
                    BsB + (wid * 32 + j * 8) * 128);
        }
        __syncthreads();
#pragma unroll
        for (int ks = 0; ks < 2; ++ks) {
            half8 af[4];
#pragma unroll
            for (int mt = 0; mt < 4; ++mt) {
                int row = wm * 64 + mt * 16 + c;
                af[mt] = *(const half8*)(AsB + row * 128 +
                         ((ks * 64 + g * 16) ^ ((row & 7) << 4)));
            }
#pragma unroll
            for (int nt = 0; nt < 4; ++nt) {
                int row = wn * 64 + nt * 16 + c;
                half8 bf = *(const half8*)(BsB + row * 128 +
                           ((ks * 64 + g * 16) ^ ((row & 7) << 4)));
#pragma unroll
                for (int mt = 0; mt < 4; ++mt)
                    acc[mt][nt] = __builtin_amdgcn_mfma_f32_16x16x32_f16(
                        af[mt], bf, acc[mt][nt], 0, 0, 0);
            }
        }
    }
#pragma unroll
    for (int nt = 0; nt < 4; ++nt) {
        int n = n0 + wn * 64 + nt * 16 + c;
        float bn = bias[n];
#pragma unroll
        for (int mt = 0; mt < 4; ++mt)
#pragma unroll
            for (int reg = 0; reg < 4; ++reg) {
                int m = m0 + wm * 64 + mt * 16 + 4 * g + reg;
                out[(size_t)m * DD + n] = acc[mt][nt][reg] + bn;
            }
    }
}

extern "C" void kernel_launch(void* const* d_in, const int* in_sizes, int n_in,
                              void* d_out, int out_size, void* d_ws, size_t ws_size,
                              hipStream_t stream)
{
    (void)in_sizes; (void)n_in; (void)out_size; (void)ws_size;

    const float* query = (const float*)d_in[0];
    const float* key   = (const float*)d_in[1];
    const float* value = (const float*)d_in[2];
    const int*   mask  = (const int*)d_in[3];
    const float* rpb   = (const float*)d_in[4];
    const float* Wq = (const float*)d_in[5];  const float* bq = (const float*)d_in[6];
    const float* Wk = (const float*)d_in[7];  const float* bk = (const float*)d_in[8];
    const float* Wv = (const float*)d_in[9];  const float* bv = (const float*)d_in[10];
    const float* Wo = (const float*)d_in[11]; const float* bo = (const float*)d_in[12];
    float* out = (float*)d_out;

    // workspace layout (f16 elements). AOh aliases Xq (dead after prep_big).
    const size_t NX = (size_t)2 * SS * DD;   // 4096x1024
    const size_t NW = (size_t)DD * DD;       // 1024x1024
    f16* Xq    = (f16*)d_ws;
    f16* Xk    = Xq + NX;
    f16* Xv    = Xk + NX;
    f16* WqT   = Xv + NX;
    f16* WkT   = WqT + NW;
    f16* WvT   = WkT + NW;
    f16* WoT   = WvT + NW;
    f16* Qw    = WoT + NW;
    f16* Kw    = Qw + NX;
    f16* VTw   = Kw + NX;
    f16* rpbT  = VTw + NX;                   // 16*2048*2048 f16 = 128 MB
    u64* mbits = (u64*)(rpbT + (size_t)HH * SS * SS);  // 1 MB
    f16* AOh   = Xq;   // alias

    prep_xw<<<dim3(7168), 256, 0, stream>>>(query, key, value, Xq, Xk, Xv,
                                            Wq, Wk, Wv, Wo, WqT, WkT, WvT, WoT);
    prep_big<<<dim3(5888), 256, 0, stream>>>(Xq, Xk, Xv, WqT, WkT, WvT,
                                             bq, bk, bv, Qw, Kw, VTw,
                                             rpb, rpbT, mask, mbits);
    attn_fwd<<<dim3(2 * HH, SS / 64), 256, 0, stream>>>(Qw, Kw, VTw, rpbT, mbits, AOh);
    gemm_out<<<dim3(8, 32), 256, 0, stream>>>(AOh, WoT, bo, out);
}